// Round 1
// baseline (457.375 us; speedup 1.0000x reference)
//
#include <hip/hip_runtime.h>

// ComparatorNBit: A,B are [N,32] float32 in {0,1}, MSB first.
// a_eq_b = all bits equal; a_gt_b = unsigned compare of packed 32-bit words.
//
// R8: MLP + block-turnover fix. Previous structure (R5-R7) issued only 2
// loads per thread then stalled the wave on vmcnt(0) for the ballots, with
// 62,500 one-shot blocks whose lifetime ~= one HBM latency -> CU idles on
// block turnover; reads ran at 3.46 TB/s vs 6.7 TB/s write BW shown by the
// harness fills in the same graph.
// Change: 4 float4-pairs per thread (8 independent loads, ALL issued before
// first use -> 4x in-flight bytes per wave), grid 62,500 -> 15,625 blocks,
// and an all-64-lane branchless store phase (ballot masks are wave-uniform
// SGPRs, so lane l serves chunk l>>4, role l&8, row-in-wave l&7).
// Prediction: kernel 148 -> ~95-115 us, total 454.7 -> ~400-420 us.
// If neutral, the ~3.5 TB/s read ceiling is confirmed with saturated MLP.

typedef float vfloat4 __attribute__((ext_vector_type(4)));

__device__ __forceinline__ void nibble_masks(vfloat4 a, vfloat4 b,
                                             unsigned long long& d,
                                             unsigned long long& t) {
    // Pack 4 consecutive elements into a nibble, MSB-first.
    unsigned an = ((unsigned)(a.x > 0.5f) << 3) | ((unsigned)(a.y > 0.5f) << 2) |
                  ((unsigned)(a.z > 0.5f) << 1) |  (unsigned)(a.w > 0.5f);
    unsigned bn = ((unsigned)(b.x > 0.5f) << 3) | ((unsigned)(b.y > 0.5f) << 2) |
                  ((unsigned)(b.z > 0.5f) << 1) |  (unsigned)(b.w > 0.5f);
    // Wave-wide nibble-compare masks; byte g = row g's 8 nibble results,
    // bit k within the byte = nibble k (k=0 most significant).
    d = __ballot(an != bn);
    t = __ballot(an > bn);
}

__global__ void __launch_bounds__(256)
comparator_kernel(const vfloat4* __restrict__ A, const vfloat4* __restrict__ B,
                  float* __restrict__ out_gt, float* __restrict__ out_eq) {
    const int tid = threadIdx.x;
    const long long blockBase = (long long)blockIdx.x * 1024;  // float4 units

    // Issue all 8 loads before any dependent use: 4x the in-flight bytes of
    // the previous 2-load structure. Chunks are wave-aligned 256-float4
    // slabs so the ballot packing per chunk is identical to R5-R7.
    vfloat4 a0 = __builtin_nontemporal_load(&A[blockBase +   0 + tid]);
    vfloat4 b0 = __builtin_nontemporal_load(&B[blockBase +   0 + tid]);
    vfloat4 a1 = __builtin_nontemporal_load(&A[blockBase + 256 + tid]);
    vfloat4 b1 = __builtin_nontemporal_load(&B[blockBase + 256 + tid]);
    vfloat4 a2 = __builtin_nontemporal_load(&A[blockBase + 512 + tid]);
    vfloat4 b2 = __builtin_nontemporal_load(&B[blockBase + 512 + tid]);
    vfloat4 a3 = __builtin_nontemporal_load(&A[blockBase + 768 + tid]);
    vfloat4 b3 = __builtin_nontemporal_load(&B[blockBase + 768 + tid]);

    unsigned long long d0, t0, d1, t1, d2, t2, d3, t3;
    nibble_masks(a0, b0, d0, t0);   // waits vmcnt for a0/b0 only; rest in flight
    nibble_masks(a1, b1, d1, t1);
    nibble_masks(a2, b2, d2, t2);
    nibble_masks(a3, b3, d3, t3);

    // Store phase: all 64 lanes. Ballot results are wave-uniform, so lane l
    // handles chunk c = l>>4, role (gt/eq) = l&8, row-in-wave g = l&7.
    const int lane   = tid & 63;
    const int c      = lane >> 4;
    const int g      = lane & 7;
    const bool is_eq = (lane & 8) != 0;

    // Named-variable selects (no runtime-indexed array -> no scratch).
    const unsigned long long dc =
        (c & 2) ? ((c & 1) ? d3 : d2) : ((c & 1) ? d1 : d0);
    const unsigned long long tc =
        (c & 2) ? ((c & 1) ? t3 : t2) : ((c & 1) ? t1 : t0);

    const unsigned db = (unsigned)(dc >> (8 * g)) & 0xFFu;
    const unsigned tb = (unsigned)(tc >> (8 * g)) & 0xFFu;

    const unsigned msdiff = db & (0u - db);           // most significant differing nibble
    const float gtv = (tb & msdiff) ? 1.0f : 0.0f;
    const float eqv = (db == 0u)    ? 1.0f : 0.0f;

    // chunk's wave-base vec = blockBase + c*256 + (tid & 192); row = vec/8 + g
    const long long row =
        ((blockBase + (long long)c * 256 + (tid & 192)) >> 3) + g;

    float* p = is_eq ? (out_eq + row) : (out_gt + row);
    __builtin_nontemporal_store(is_eq ? eqv : gtv, p);
}

extern "C" void kernel_launch(void* const* d_in, const int* in_sizes, int n_in,
                              void* d_out, int out_size, void* d_ws, size_t ws_size,
                              hipStream_t stream) {
    const vfloat4* A = (const vfloat4*)d_in[0];
    const vfloat4* B = (const vfloat4*)d_in[1];
    float* out = (float*)d_out;

    const int BITS = 32;
    long long n = in_sizes[0] / BITS;      // 2,000,000 rows

    float* out_gt = out;                   // output 0: a_gt_b [N]
    float* out_eq = out + n;               // output 1: a_eq_b [N]

    long long totalVec = n * 8;            // 16,000,000 float4s per input
    long long grid = totalVec / 1024;      // 15,625 blocks, exact (n % 128 == 0)
    comparator_kernel<<<(int)grid, 256, 0, stream>>>(A, B, out_gt, out_eq);
}